// Round 19
// baseline (145.450 us; speedup 1.0000x reference)
//
#include <hip/hip_runtime.h>
#include <math.h>

#define EMB 768
#define MSUB 32
#define KCODE 256
#define DSUB 24
#define NQ 1024
#define NTOT 5120    // 1024 docs + 4096 negs
#define NCOLS 5120
#define DPAD 32      // padded subvector dim for MFMA (K=32)
#define L2E 1.4426950408889634f
#define LN2 0.6931471805599453f

// prep kernel section sizes (16B work items)
#define CVT4 ((NQ * EMB + NQ * EMB + 4096 * EMB + EMB * EMB) / 4)
#define GATW (NTOT * 192)
#define PADW (NTOT * MSUB)
#define CBPW (MSUB * KCODE)

typedef __attribute__((ext_vector_type(8))) short short8;
typedef __attribute__((ext_vector_type(4))) float floatx4;

__device__ __forceinline__ unsigned short f2bf(float f) {
    unsigned int u = __float_as_uint(f);
    unsigned int r = (u + 0x7FFFu + ((u >> 16) & 1u)) >> 16;   // RNE
    return (unsigned short)r;
}
__device__ __forceinline__ float bf2f(unsigned short h) {
    return __uint_as_float((unsigned int)h << 16);
}

__device__ __forceinline__ void gload16(const void* g, void* l) {
    __builtin_amdgcn_global_load_lds(
        (const __attribute__((address_space(1))) void*)g,
        (__attribute__((address_space(3))) void*)l, 16, 0, 0);
}

#define BKG 32
#define BMS 128
#define BNS 128

// ============ rotation GEMM: 64x128, 2-buf + register fragment prefetch ============
#define BMR 64
#define BNR 128
__global__ __launch_bounds__(256) void gemm_rot(
    const unsigned short* __restrict__ A, const unsigned short* __restrict__ B,
    unsigned short* __restrict__ Cb, const unsigned short* __restrict__ ccb,
    unsigned short* __restrict__ subp)
{
    __shared__ __align__(16) unsigned short As[2][BMR * BKG];   // 2 x 4 KB
    __shared__ __align__(16) unsigned short Bs[2][BNR * BKG];   // 2 x 8 KB = 24 KB
    const int tid  = threadIdx.x;
    const int wave = tid >> 6;
    const int lane = tid & 63;
    const int wr = wave >> 1, wc = wave & 1;
    const int row0 = blockIdx.y * BMR;
    const int col0 = blockIdx.x * BNR;

    const int ar  = tid >> 2, aks  = (tid & 3) ^ ((ar >> 1) & 3);
    const unsigned short* Ap = A + (size_t)(row0 + ar) * EMB + aks * 8;
    const int br0 = tid >> 2,        bks0 = (tid & 3) ^ ((br0 >> 1) & 3);
    const int br1 = 64 + (tid >> 2), bks1 = (tid & 3) ^ ((br1 >> 1) & 3);
    const unsigned short* Bp0 = B + (size_t)(col0 + br0) * EMB + bks0 * 8;
    const unsigned short* Bp1 = B + (size_t)(col0 + br1) * EMB + bks1 * 8;

    const int frow = lane & 15;
    const int kblk = lane >> 4;
    int aoff[2], boff[4];
#pragma unroll
    for (int m = 0; m < 2; ++m) {
        const int r = wr * 32 + m * 16 + frow;
        aoff[m] = (r * 4 + (kblk ^ ((r >> 1) & 3))) * 8;
    }
#pragma unroll
    for (int n = 0; n < 4; ++n) {
        const int c = wc * 64 + n * 16 + frow;
        boff[n] = (c * 4 + (kblk ^ ((c >> 1) & 3))) * 8;
    }

    floatx4 acc[2][4];
#pragma unroll
    for (int m = 0; m < 2; ++m)
#pragma unroll
        for (int n = 0; n < 4; ++n)
            acc[m][n] = (floatx4){0.f, 0.f, 0.f, 0.f};

    auto STAGE = [&](int buf, int k0) {
        gload16(Ap + k0, &As[buf][tid * 8]);
        gload16(Bp0 + k0, &Bs[buf][tid * 8]);
        gload16(Bp1 + k0, &Bs[buf][(tid + 256) * 8]);
    };

#define LDFRAG_R(buf, af, bf)                                                  \
    {                                                                          \
        _Pragma("unroll")                                                      \
        for (int m = 0; m < 2; ++m) af[m] = *(const short8*)&As[buf][aoff[m]]; \
        _Pragma("unroll")                                                      \
        for (int n = 0; n < 4; ++n) bf[n] = *(const short8*)&Bs[buf][boff[n]]; \
    }
#define MFMA_R(af, bf)                                                         \
    {                                                                          \
        _Pragma("unroll")                                                      \
        for (int m = 0; m < 2; ++m)                                            \
            _Pragma("unroll")                                                  \
            for (int n = 0; n < 4; ++n)                                        \
                acc[m][n] = __builtin_amdgcn_mfma_f32_16x16x32_bf16(           \
                    af[m], bf[n], acc[m][n], 0, 0, 0);                         \
    }

    short8 af0[2], bf0[4], af1[2], bf1[4];
    const int NT = EMB / BKG;   // 24 (even)

    STAGE(0, 0);
    asm volatile("s_waitcnt vmcnt(0)" ::: "memory");
    __builtin_amdgcn_s_barrier();
    asm volatile("" ::: "memory");
    LDFRAG_R(0, af0, bf0);
    STAGE(1, BKG);

    for (int it = 0; it < NT; it += 2) {
        asm volatile("s_waitcnt vmcnt(0) lgkmcnt(0)" ::: "memory");
        __builtin_amdgcn_s_barrier();
        asm volatile("" ::: "memory");
        if (it + 2 < NT) STAGE(0, (it + 2) * BKG);
        LDFRAG_R(1, af1, bf1);
        MFMA_R(af0, bf0);

        asm volatile("s_waitcnt vmcnt(0) lgkmcnt(0)" ::: "memory");
        __builtin_amdgcn_s_barrier();
        asm volatile("" ::: "memory");
        if (it + 3 < NT) STAGE(1, (it + 3) * BKG);
        if (it + 2 < NT) LDFRAG_R(0, af0, bf0);
        MFMA_R(af1, bf1);
    }
#undef LDFRAG_R
#undef MFMA_R

    const int crow = row0 + wr * 32 + (lane >> 4) * 4;
    const int ccol = col0 + wc * 64 + (lane & 15);
#pragma unroll
    for (int m = 0; m < 2; ++m)
#pragma unroll
        for (int n = 0; n < 4; ++n)
#pragma unroll
            for (int r = 0; r < 4; ++r) {
                const int rr = crow + m * 16 + r;
                const int cc = ccol + n * 16;
                const float v = acc[m][n][r];
                Cb[(size_t)rr * EMB + cc] = f2bf(v);
                if (rr >= NQ) {
                    const int nn = rr - NQ;
                    const float cen = bf2f(ccb[(size_t)nn * EMB + cc]);
                    const unsigned mm = (unsigned)cc / 24u;
                    const unsigned jj = (unsigned)cc - mm * 24u;
                    subp[(size_t)nn * (MSUB * DPAD) + mm * DPAD + jj] = f2bf(v - cen);
                }
            }
}

// ====== z-batched score GEMM: 128x128, 2-buf + reg prefetch + setprio(MFMA) =======
__global__ __launch_bounds__(256) void gemm_score4(
    const unsigned short* __restrict__ A0, const unsigned short* __restrict__ B0, unsigned short* __restrict__ C0,
    const unsigned short* __restrict__ A1, const unsigned short* __restrict__ B1, unsigned short* __restrict__ C1,
    const unsigned short* __restrict__ A2, const unsigned short* __restrict__ B2, unsigned short* __restrict__ C2,
    const unsigned short* __restrict__ A3, const unsigned short* __restrict__ B3, unsigned short* __restrict__ C3)
{
    const unsigned short* A; const unsigned short* B; unsigned short* C;
    switch (blockIdx.z) {
        case 0:  A = A0; B = B0; C = C0; break;
        case 1:  A = A1; B = B1; C = C1; break;
        case 2:  A = A2; B = B2; C = C2; break;
        default: A = A3; B = B3; C = C3; break;
    }

    __shared__ __align__(16) unsigned short As[2][BMS * BKG];   // 2 x 8 KB
    __shared__ __align__(16) unsigned short Bs[2][BNS * BKG];   // 2 x 8 KB = 32 KB
    const int tid  = threadIdx.x;
    const int wave = tid >> 6;
    const int lane = tid & 63;
    const int wr = wave >> 1, wc = wave & 1;
    const int row0 = blockIdx.y * BMS;
    const int col0 = blockIdx.x * BNS;

    const int g0 = tid, g1 = tid + 256;
    const int ar0 = g0 >> 2, as0 = (g0 & 3) ^ ((ar0 >> 1) & 3);
    const int ar1 = g1 >> 2, as1 = (g1 & 3) ^ ((ar1 >> 1) & 3);
    const unsigned short* Ap0 = A + (size_t)(row0 + ar0) * EMB + as0 * 8;
    const unsigned short* Ap1 = A + (size_t)(row0 + ar1) * EMB + as1 * 8;
    const unsigned short* Bp0 = B + (size_t)(col0 + ar0) * EMB + as0 * 8;
    const unsigned short* Bp1 = B + (size_t)(col0 + ar1) * EMB + as1 * 8;

    const int frow = lane & 15;
    const int kblk = lane >> 4;
    int aoff[4], boff[4];
#pragma unroll
    for (int m = 0; m < 4; ++m) {
        const int r = wr * 64 + m * 16 + frow;
        aoff[m] = (r * 4 + (kblk ^ ((r >> 1) & 3))) * 8;
        const int c = wc * 64 + m * 16 + frow;
        boff[m] = (c * 4 + (kblk ^ ((c >> 1) & 3))) * 8;
    }

    floatx4 acc[4][4];
#pragma unroll
    for (int m = 0; m < 4; ++m)
#pragma unroll
        for (int n = 0; n < 4; ++n)
            acc[m][n] = (floatx4){0.f, 0.f, 0.f, 0.f};

    auto STAGE = [&](int buf, int k0) {
        gload16(Ap0 + k0, &As[buf][g0 * 8]);
        gload16(Ap1 + k0, &As[buf][g1 * 8]);
        gload16(Bp0 + k0, &Bs[buf][g0 * 8]);
        gload16(Bp1 + k0, &Bs[buf][g1 * 8]);
    };

#define LDFRAG_S(buf, af, bf)                                                  \
    {                                                                          \
        _Pragma("unroll")                                                      \
        for (int m = 0; m < 4; ++m) af[m] = *(const short8*)&As[buf][aoff[m]]; \
        _Pragma("unroll")                                                      \
        for (int n = 0; n < 4; ++n) bf[n] = *(const short8*)&Bs[buf][boff[n]]; \
    }
#define MFMA_S(af, bf)                                                         \
    {                                                                          \
        __builtin_amdgcn_s_setprio(1);                                         \
        _Pragma("unroll")                                                      \
        for (int m = 0; m < 4; ++m)                                            \
            _Pragma("unroll")                                                  \
            for (int n = 0; n < 4; ++n)                                        \
                acc[m][n] = __builtin_amdgcn_mfma_f32_16x16x32_bf16(           \
                    af[m], bf[n], acc[m][n], 0, 0, 0);                         \
        __builtin_amdgcn_s_setprio(0);                                         \
    }

    short8 af0[4], bf0[4], af1[4], bf1[4];
    const int NT = EMB / BKG;   // 24 (even)

    STAGE(0, 0);
    asm volatile("s_waitcnt vmcnt(0)" ::: "memory");
    __builtin_amdgcn_s_barrier();
    asm volatile("" ::: "memory");
    LDFRAG_S(0, af0, bf0);
    STAGE(1, BKG);

    for (int it = 0; it < NT; it += 2) {
        asm volatile("s_waitcnt vmcnt(0) lgkmcnt(0)" ::: "memory");
        __builtin_amdgcn_s_barrier();
        asm volatile("" ::: "memory");
        if (it + 2 < NT) STAGE(0, (it + 2) * BKG);
        LDFRAG_S(1, af1, bf1);
        MFMA_S(af0, bf0);

        asm volatile("s_waitcnt vmcnt(0) lgkmcnt(0)" ::: "memory");
        __builtin_amdgcn_s_barrier();
        asm volatile("" ::: "memory");
        if (it + 3 < NT) STAGE(1, (it + 3) * BKG);
        if (it + 2 < NT) LDFRAG_S(0, af0, bf0);
        MFMA_S(af1, bf1);
    }
#undef LDFRAG_S
#undef MFMA_S

    const int crow = row0 + wr * 64 + (lane >> 4) * 4;
    const int ccol = col0 + wc * 64 + (lane & 15);
#pragma unroll
    for (int m = 0; m < 4; ++m)
#pragma unroll
        for (int n = 0; n < 4; ++n)
#pragma unroll
            for (int r = 0; r < 4; ++r)
                C[(size_t)(crow + m * 16 + r) * NCOLS + ccol + n * 16] = f2bf(acc[m][n][r]);
}

// ============ fused prep: out-zero + cvt + IVF gather (dense) + pad-zero + cbprep ===
__global__ __launch_bounds__(256) void prep_kernel(
    const float* __restrict__ q, const float* __restrict__ d,
    const float* __restrict__ n, const float* __restrict__ rot,
    const float* __restrict__ cb, const float* __restrict__ ivf,
    const int* __restrict__ doc_ids, const int* __restrict__ neg_ids,
    unsigned short* __restrict__ qdnb, unsigned short* __restrict__ rotb,
    unsigned short* __restrict__ ccb, unsigned short* __restrict__ subp,
    unsigned short* __restrict__ cbb, float* __restrict__ bias,
    float* __restrict__ out, int out_n)
{
    int i = blockIdx.x * 256 + threadIdx.x;

    if (i < CVT4) {
        const int S1 = NQ * EMB / 4;
        const int S2 = S1 + NQ * EMB / 4;
        const int S3 = S2 + 4096 * EMB / 4;
        const float* src; unsigned short* dst; int off;
        if (i < S1)      { src = q;   dst = qdnb;                        off = i; }
        else if (i < S2) { src = d;   dst = qdnb + (size_t)NQ * EMB;     off = i - S1; }
        else if (i < S3) { src = n;   dst = qdnb + (size_t)2 * NQ * EMB; off = i - S2; }
        else             { src = rot; dst = rotb;                        off = i - S3; }
        const float4 v = ((const float4*)src)[off];
        ushort4 b;
        b.x = f2bf(v.x); b.y = f2bf(v.y); b.z = f2bf(v.z); b.w = f2bf(v.w);
        ((ushort4*)dst)[off] = b;
        return;
    }
    i -= CVT4;

    if (i < GATW) {
        const int row = i / 192, t = i - row * 192;   // dense: all lanes active
        const int id = (row < NQ) ? doc_ids[row] : neg_ids[row - NQ];
        const float4 v = ((const float4*)(ivf + (size_t)id * EMB))[t];
        ushort4 b;
        b.x = f2bf(v.x); b.y = f2bf(v.y); b.z = f2bf(v.z); b.w = f2bf(v.w);
        ((ushort4*)(ccb + (size_t)row * EMB))[t] = b;
        return;
    }
    i -= GATW;

    if (i < PADW) {
        const int nn = i >> 5, mm = i & 31;
        *(uint4*)(subp + (size_t)nn * (MSUB * DPAD) + mm * DPAD + DSUB) =
            make_uint4(0u, 0u, 0u, 0u);
        return;
    }
    i -= PADW;

    if (i < CBPW) {
        const float* cp = cb + (size_t)i * DSUB;
        unsigned short o[DPAD];
        float ss = 0.f;
#pragma unroll
        for (int j = 0; j < 6; ++j) {
            const float4 v = *(const float4*)(cp + j * 4);
            o[j * 4 + 0] = f2bf(v.x); o[j * 4 + 1] = f2bf(v.y);
            o[j * 4 + 2] = f2bf(v.z); o[j * 4 + 3] = f2bf(v.w);
            ss = fmaf(v.x, v.x, ss); ss = fmaf(v.y, v.y, ss);
            ss = fmaf(v.z, v.z, ss); ss = fmaf(v.w, v.w, ss);
        }
#pragma unroll
        for (int j = DSUB; j < DPAD; ++j) o[j] = 0;
        unsigned short* op = cbb + (size_t)i * DPAD;
#pragma unroll
        for (int j = 0; j < DPAD / 4; ++j)
            ((ushort4*)op)[j] = make_ushort4(o[j*4], o[j*4+1], o[j*4+2], o[j*4+3]);
        bias[i] = 0.5f * ss;
        return;
    }
    i -= CBPW;

    if (i < 64 && i < out_n) out[i] = 0.f;
}

// ============ PQ argmin via MFMA + fused reconstruct ============
__global__ __launch_bounds__(256) void pq_mfma_argmin(
    const unsigned short* __restrict__ subp,   // [NTOT][MSUB*DPAD]
    const unsigned short* __restrict__ cbb,    // [MSUB][KCODE][DPAD]
    const float* __restrict__ bias,            // [MSUB][KCODE]
    const unsigned short* __restrict__ ccb,    // [NTOT][EMB]
    unsigned short* __restrict__ pqb)          // [NTOT][EMB]
{
    const int m = blockIdx.y;
    const int row0 = blockIdx.x * 128;
    __shared__ __align__(16) unsigned short As[128 * DPAD];   // 8 KB
    __shared__ __align__(16) unsigned short Bs[KCODE * DPAD]; // 16 KB
    __shared__ __align__(16) float bs[KCODE];                 // 1 KB
    __shared__ unsigned char kbest[128];
    const int tid = threadIdx.x;
    const int wave = tid >> 6, lane = tid & 63;

    {
        const int g = tid;
        const int r = g >> 2, kc = (g & 3) ^ ((r >> 1) & 3);
        gload16(subp + (size_t)(row0 + r) * (MSUB * DPAD) + m * DPAD + kc * 8, &As[g * 8]);
    }
    {
        const int g = tid + 256;
        const int r = g >> 2, kc = (g & 3) ^ ((r >> 1) & 3);
        gload16(subp + (size_t)(row0 + r) * (MSUB * DPAD) + m * DPAD + kc * 8, &As[g * 8]);
    }
#pragma unroll
    for (int i = 0; i < 4; ++i) {
        const int g = tid + i * 256;
        const int r = g >> 2, kc = (g & 3) ^ ((r >> 1) & 3);
        gload16(cbb + (size_t)m * (KCODE * DPAD) + r * DPAD + kc * 8, &Bs[g * 8]);
    }
    if (tid < 64) gload16(bias + m * KCODE + tid * 4, &bs[tid * 4]);
    __syncthreads();

    const int frow = lane & 15, kblk = lane >> 4;
    short8 af[2];
#pragma unroll
    for (int t = 0; t < 2; ++t) {
        const int r = wave * 32 + t * 16 + frow;
        af[t] = *(const short8*)&As[(r * 4 + (kblk ^ ((r >> 1) & 3))) * 8];
    }
    unsigned best[2][4];
#pragma unroll
    for (int t = 0; t < 2; ++t)
#pragma unroll
        for (int r = 0; r < 4; ++r) best[t][r] = 0xFFFFFFFFu;

#pragma unroll
    for (int n = 0; n < 16; ++n) {
        const int br = n * 16 + frow;
        const short8 bf = *(const short8*)&Bs[(br * 4 + (kblk ^ ((br >> 1) & 3))) * 8];
        const float bv = bs[br];
        const unsigned kid = (unsigned)br;
        floatx4 a0 = __builtin_amdgcn_mfma_f32_16x16x32_bf16(
            af[0], bf, (floatx4){0.f, 0.f, 0.f, 0.f}, 0, 0, 0);
        floatx4 a1 = __builtin_amdgcn_mfma_f32_16x16x32_bf16(
            af[1], bf, (floatx4){0.f, 0.f, 0.f, 0.f}, 0, 0, 0);
#pragma unroll
        for (int r = 0; r < 4; ++r) {
            const float d0 = bv - a0[r];
            const float d1 = bv - a1[r];
            unsigned u0 = __float_as_uint(d0); u0 ^= (unsigned)((int)u0 >> 31) | 0x80000000u;
            unsigned u1 = __float_as_uint(d1); u1 ^= (unsigned)((int)u1 >> 31) | 0x80000000u;
            best[0][r] = min(best[0][r], (u0 & 0xFFFFFF00u) | kid);
            best[1][r] = min(best[1][r], (u1 & 0xFFFFFF00u) | kid);
        }
    }
#pragma unroll
    for (int off = 1; off <= 8; off <<= 1)
#pragma unroll
        for (int t = 0; t < 2; ++t)
#pragma unroll
            for (int r = 0; r < 4; ++r)
                best[t][r] = min(best[t][r], (unsigned)__shfl_xor((int)best[t][r], off));
    if (frow == 0) {
        const int rbase = wave * 32 + kblk * 4;
#pragma unroll
        for (int t = 0; t < 2; ++t)
#pragma unroll
            for (int r = 0; r < 4; ++r)
                kbest[rbase + t * 16 + r] = (unsigned char)(best[t][r] & 0xFFu);
    }
    __syncthreads();

    if (tid < 128) {
        const int row = row0 + tid;
        const int k = kbest[tid];
        const unsigned short* cbp = cbb + ((size_t)m * KCODE + k) * DPAD;
        const unsigned short* ccp = ccb + (size_t)row * EMB + m * DSUB;
        unsigned short* op = pqb + (size_t)row * EMB + m * DSUB;
#pragma unroll
        for (int j = 0; j < 6; ++j) {
            const ushort4 cw = ((const ushort4*)cbp)[j];
            const ushort4 cc = ((const ushort4*)ccp)[j];
            ushort4 o;
            o.x = f2bf(bf2f(cw.x) + bf2f(cc.x)); o.y = f2bf(bf2f(cw.y) + bf2f(cc.y));
            o.z = f2bf(bf2f(cw.z) + bf2f(cc.z)); o.w = f2bf(bf2f(cw.w) + bf2f(cc.w));
            ((ushort4*)op)[j] = o;
        }
    }
}

// ============ loss: block per (row, ls); teacher stats inline; 5 slot reductions ====
__global__ __launch_bounds__(256) void loss3_kernel(
    const unsigned short* __restrict__ Tb, const unsigned short* __restrict__ S0b,
    const unsigned short* __restrict__ S1b, const unsigned short* __restrict__ S2b,
    float* __restrict__ out, float scale)
{
    const int row = blockIdx.x;
    const int ls = blockIdx.y;
    const unsigned short* S = (ls == 0) ? S0b : ((ls == 1) ? S1b : S2b);
    const int t = threadIdx.x, wid = t >> 6, lane = t & 63;
    __shared__ float red[5][4];

    auto blk_max = [&](float v, int slot) -> float {
#pragma unroll
        for (int off = 32; off >= 1; off >>= 1) v = fmaxf(v, __shfl_xor(v, off));
        if (lane == 0) red[slot][wid] = v;
        __syncthreads();
        return fmaxf(fmaxf(red[slot][0], red[slot][1]),
                     fmaxf(red[slot][2], red[slot][3]));
    };
    auto blk_sum = [&](float v, int slot) -> float {
#pragma unroll
        for (int off = 32; off >= 1; off >>= 1) v += __shfl_xor(v, off);
        if (lane == 0) red[slot][wid] = v;
        __syncthreads();
        return red[slot][0] + red[slot][1] + red[slot][2] + red[slot][3];
    };

    const ushort4* t4 = (const ushort4*)(Tb + (size_t)row * NCOLS);
    const ushort4* s4 = (const ushort4*)(S + (size_t)row * NCOLS);
    float tv[20], sv[20];
#pragma unroll
    for (int i = 0; i < 5; ++i) {
        const ushort4 ut = t4[t + i * 256];
        const ushort4 us = s4[t + i * 256];
        tv[i*4+0] = bf2f(ut.x); tv[i*4+1] = bf2f(ut.y);
        tv[i*4+2] = bf2f(ut.z); tv[i*4+3] = bf2f(ut.w);
        sv[i*4+0] = bf2f(us.x); sv[i*4+1] = bf2f(us.y);
        sv[i*4+2] = bf2f(us.z); sv[i*4+3] = bf2f(us.w);
    }

    float pm = -3.4e38f, qm = -3.4e38f;
#pragma unroll
    for (int j = 0; j < 20; ++j) { pm = fmaxf(pm, tv[j]); qm = fmaxf(qm, sv[j]); }
    const float tm = blk_max(pm, 0);
    const float sm = blk_max(qm, 1);

    float ps = 0.f, ss = 0.f;
#pragma unroll
    for (int j = 0; j < 20; ++j) {
        ps += __builtin_amdgcn_exp2f((tv[j] - tm) * L2E);
        ss += __builtin_amdgcn_exp2f((sv[j] - sm) * L2E);
    }
    const float inv_t = 1.f / blk_sum(ps, 2);
    const float inv_s = 1.f / blk_sum(ss, 3);

    float acc = 0.f;
#pragma unroll
    for (int j = 0; j < 20; ++j) {
        const float tp = __builtin_amdgcn_exp2f((tv[j] - tm) * L2E) * inv_t;
        acc += tp * __builtin_amdgcn_logf(
            __builtin_amdgcn_exp2f((sv[j] - sm) * L2E) * inv_s + 1e-6f);
    }
    const float tot = blk_sum(acc, 4);
    if (t == 0) atomicAdd(out + ls, -tot * LN2 * scale);
}

// ============ launch ============
extern "C" void kernel_launch(void* const* d_in, const int* in_sizes, int n_in,
                              void* d_out, int out_size, void* d_ws, size_t ws_size,
                              hipStream_t stream)
{
    const float* q    = (const float*)d_in[0];
    const float* dpos = (const float*)d_in[1];
    const float* nneg = (const float*)d_in[2];
    const float* rot  = (const float*)d_in[3];
    const float* cb   = (const float*)d_in[4];
    const float* ivf  = (const float*)d_in[5];
    const int* doc_ids = (const int*)d_in[6];
    const int* neg_ids = (const int*)d_in[7];
    float* out = (float*)d_out;

    char* p = (char*)d_ws;
    auto take = [&](size_t bytes) { char* r = p; p += (bytes + 255) & ~(size_t)255; return r; };
    unsigned short* qdnb  = (unsigned short*)take((size_t)(NQ + NTOT) * EMB * 2);
    unsigned short* rqdnb = (unsigned short*)take((size_t)(NQ + NTOT) * EMB * 2);
    unsigned short* rotb  = (unsigned short*)take((size_t)EMB * EMB * 2);
    unsigned short* ccb   = (unsigned short*)take((size_t)NTOT * EMB * 2);
    unsigned short* pqb   = (unsigned short*)take((size_t)NTOT * EMB * 2);
    unsigned short* cbb   = (unsigned short*)take((size_t)MSUB * KCODE * DPAD * 2);
    float*          bias  = (float*)take((size_t)MSUB * KCODE * 4);
    unsigned short* subp  = (unsigned short*)take((size_t)NTOT * MSUB * DPAD * 2);
    unsigned short* Tb    = (unsigned short*)take((size_t)NQ * NCOLS * 2);
    unsigned short* S0b   = (unsigned short*)take((size_t)NQ * NCOLS * 2);
    unsigned short* S1b   = (unsigned short*)take((size_t)NQ * NCOLS * 2);
    unsigned short* S2b   = (unsigned short*)take((size_t)NQ * NCOLS * 2);

    unsigned short* qb   = qdnb;
    unsigned short* dnb  = qdnb + (size_t)NQ * EMB;
    unsigned short* rqb  = rqdnb;
    unsigned short* rdnb = rqdnb + (size_t)NQ * EMB;

    const float scale = 1.f / NQ;

    // 1) fused prep: out-zero + cvt + IVF gather (dense) + subp-pad-zero + cbprep
    const int prepW = CVT4 + GATW + PADW + CBPW + 64;
    prep_kernel<<<(prepW + 255) / 256, 256, 0, stream>>>(
        q, dpos, nneg, rot, cb, ivf, doc_ids, neg_ids,
        qdnb, rotb, ccb, subp, cbb, bias, out, out_size);

    // 2) rotation: [q;d;n] @ rot^T -> rqdnb bf16; rows >= NQ also subp residual
    gemm_rot<<<dim3(EMB / BNR, (NQ + NTOT) / BMR), 256, 0, stream>>>(
        qdnb, rotb, rqdnb, ccb, subp);

    // 3) PQ argmin (MFMA) with fused reconstruct -> pqb
    pq_mfma_argmin<<<dim3(NTOT / 128, MSUB), 256, 0, stream>>>(
        subp, cbb, bias, ccb, pqb);

    // 4) all four score GEMMs in one z=4 dispatch (bf16 outputs, 1280 blocks = 5/CU)
    gemm_score4<<<dim3(NCOLS / BNS, NQ / BMS, 4), 256, 0, stream>>>(
        qb, dnb, Tb,  rqb, rdnb, S0b,  rqb, ccb, S1b,  rqb, pqb, S2b);

    // 5) three losses, block per (row, ls)
    loss3_kernel<<<dim3(NQ, 3), 256, 0, stream>>>(Tb, S0b, S1b, S2b, out, scale);
}

// Round 20
// 143.358 us; speedup vs baseline: 1.0146x; 1.0146x over previous
//
#include <hip/hip_runtime.h>
#include <math.h>

#define EMB 768
#define MSUB 32
#define KCODE 256
#define DSUB 24
#define NQ 1024
#define NTOT 5120    // 1024 docs + 4096 negs
#define NCOLS 5120
#define DPAD 32      // padded subvector dim for MFMA (K=32)
#define L2E 1.4426950408889634f
#define LN2 0.6931471805599453f

// prep kernel section sizes (16B work items)
#define CVT4 ((NQ * EMB + NQ * EMB + 4096 * EMB + EMB * EMB) / 4)
#define GATW (NTOT * 192)
#define PADW (NTOT * MSUB)
#define CBPW (MSUB * KCODE)

typedef __attribute__((ext_vector_type(8))) short short8;
typedef __attribute__((ext_vector_type(4))) float floatx4;

__device__ __forceinline__ unsigned short f2bf(float f) {
    unsigned int u = __float_as_uint(f);
    unsigned int r = (u + 0x7FFFu + ((u >> 16) & 1u)) >> 16;   // RNE
    return (unsigned short)r;
}
__device__ __forceinline__ float bf2f(unsigned short h) {
    return __uint_as_float((unsigned int)h << 16);
}

__device__ __forceinline__ void gload16(const void* g, void* l) {
    __builtin_amdgcn_global_load_lds(
        (const __attribute__((address_space(1))) void*)g,
        (__attribute__((address_space(3))) void*)l, 16, 0, 0);
}

#define BKG 32
#define BMS 128
#define BNS 128

// ============ rotation GEMM: 64x128, 2-buf + register fragment prefetch ============
#define BMR 64
#define BNR 128
__global__ __launch_bounds__(256) void gemm_rot(
    const unsigned short* __restrict__ A, const unsigned short* __restrict__ B,
    unsigned short* __restrict__ Cb, const unsigned short* __restrict__ ccb,
    unsigned short* __restrict__ subp)
{
    __shared__ __align__(16) unsigned short As[2][BMR * BKG];   // 2 x 4 KB
    __shared__ __align__(16) unsigned short Bs[2][BNR * BKG];   // 2 x 8 KB = 24 KB
    const int tid  = threadIdx.x;
    const int wave = tid >> 6;
    const int lane = tid & 63;
    const int wr = wave >> 1, wc = wave & 1;
    const int row0 = blockIdx.y * BMR;
    const int col0 = blockIdx.x * BNR;

    const int ar  = tid >> 2, aks  = (tid & 3) ^ ((ar >> 1) & 3);
    const unsigned short* Ap = A + (size_t)(row0 + ar) * EMB + aks * 8;
    const int br0 = tid >> 2,        bks0 = (tid & 3) ^ ((br0 >> 1) & 3);
    const int br1 = 64 + (tid >> 2), bks1 = (tid & 3) ^ ((br1 >> 1) & 3);
    const unsigned short* Bp0 = B + (size_t)(col0 + br0) * EMB + bks0 * 8;
    const unsigned short* Bp1 = B + (size_t)(col0 + br1) * EMB + bks1 * 8;

    const int frow = lane & 15;
    const int kblk = lane >> 4;
    int aoff[2], boff[4];
#pragma unroll
    for (int m = 0; m < 2; ++m) {
        const int r = wr * 32 + m * 16 + frow;
        aoff[m] = (r * 4 + (kblk ^ ((r >> 1) & 3))) * 8;
    }
#pragma unroll
    for (int n = 0; n < 4; ++n) {
        const int c = wc * 64 + n * 16 + frow;
        boff[n] = (c * 4 + (kblk ^ ((c >> 1) & 3))) * 8;
    }

    floatx4 acc[2][4];
#pragma unroll
    for (int m = 0; m < 2; ++m)
#pragma unroll
        for (int n = 0; n < 4; ++n)
            acc[m][n] = (floatx4){0.f, 0.f, 0.f, 0.f};

    auto STAGE = [&](int buf, int k0) {
        gload16(Ap + k0, &As[buf][tid * 8]);
        gload16(Bp0 + k0, &Bs[buf][tid * 8]);
        gload16(Bp1 + k0, &Bs[buf][(tid + 256) * 8]);
    };

#define LDFRAG_R(buf, af, bf)                                                  \
    {                                                                          \
        _Pragma("unroll")                                                      \
        for (int m = 0; m < 2; ++m) af[m] = *(const short8*)&As[buf][aoff[m]]; \
        _Pragma("unroll")                                                      \
        for (int n = 0; n < 4; ++n) bf[n] = *(const short8*)&Bs[buf][boff[n]]; \
    }
#define MFMA_R(af, bf)                                                         \
    {                                                                          \
        _Pragma("unroll")                                                      \
        for (int m = 0; m < 2; ++m)                                            \
            _Pragma("unroll")                                                  \
            for (int n = 0; n < 4; ++n)                                        \
                acc[m][n] = __builtin_amdgcn_mfma_f32_16x16x32_bf16(           \
                    af[m], bf[n], acc[m][n], 0, 0, 0);                         \
    }

    short8 af0[2], bf0[4], af1[2], bf1[4];
    const int NT = EMB / BKG;   // 24 (even)

    STAGE(0, 0);
    asm volatile("s_waitcnt vmcnt(0)" ::: "memory");
    __builtin_amdgcn_s_barrier();
    asm volatile("" ::: "memory");
    LDFRAG_R(0, af0, bf0);
    STAGE(1, BKG);

    for (int it = 0; it < NT; it += 2) {
        asm volatile("s_waitcnt vmcnt(0) lgkmcnt(0)" ::: "memory");
        __builtin_amdgcn_s_barrier();
        asm volatile("" ::: "memory");
        if (it + 2 < NT) STAGE(0, (it + 2) * BKG);
        LDFRAG_R(1, af1, bf1);
        MFMA_R(af0, bf0);

        asm volatile("s_waitcnt vmcnt(0) lgkmcnt(0)" ::: "memory");
        __builtin_amdgcn_s_barrier();
        asm volatile("" ::: "memory");
        if (it + 3 < NT) STAGE(1, (it + 3) * BKG);
        if (it + 2 < NT) LDFRAG_R(0, af0, bf0);
        MFMA_R(af1, bf1);
    }
#undef LDFRAG_R
#undef MFMA_R

    const int crow = row0 + wr * 32 + (lane >> 4) * 4;
    const int ccol = col0 + wc * 64 + (lane & 15);
#pragma unroll
    for (int m = 0; m < 2; ++m)
#pragma unroll
        for (int n = 0; n < 4; ++n)
#pragma unroll
            for (int r = 0; r < 4; ++r) {
                const int rr = crow + m * 16 + r;
                const int cc = ccol + n * 16;
                const float v = acc[m][n][r];
                Cb[(size_t)rr * EMB + cc] = f2bf(v);
                if (rr >= NQ) {
                    const int nn = rr - NQ;
                    const float cen = bf2f(ccb[(size_t)nn * EMB + cc]);
                    const unsigned mm = (unsigned)cc / 24u;
                    const unsigned jj = (unsigned)cc - mm * 24u;
                    subp[(size_t)nn * (MSUB * DPAD) + mm * DPAD + jj] = f2bf(v - cen);
                }
            }
}

// ====== z-batched score GEMM: 128x128, 3-buf LDS + reg prefetch + counted vmcnt =====
// Steady iter j: wait vmcnt(4) [drains STAGE(j+2), issued 2 iters ago] + lgkm(0);
// barrier; STAGE(j+4); MFMA(j from regs); LDFRAG(j+2).  2-iteration load window.
__global__ __launch_bounds__(256) void gemm_score4(
    const unsigned short* __restrict__ A0, const unsigned short* __restrict__ B0, unsigned short* __restrict__ C0,
    const unsigned short* __restrict__ A1, const unsigned short* __restrict__ B1, unsigned short* __restrict__ C1,
    const unsigned short* __restrict__ A2, const unsigned short* __restrict__ B2, unsigned short* __restrict__ C2,
    const unsigned short* __restrict__ A3, const unsigned short* __restrict__ B3, unsigned short* __restrict__ C3)
{
    const unsigned short* A; const unsigned short* B; unsigned short* C;
    switch (blockIdx.z) {
        case 0:  A = A0; B = B0; C = C0; break;
        case 1:  A = A1; B = B1; C = C1; break;
        case 2:  A = A2; B = B2; C = C2; break;
        default: A = A3; B = B3; C = C3; break;
    }

    __shared__ __align__(16) unsigned short As[3][BMS * BKG];   // 3 x 8 KB
    __shared__ __align__(16) unsigned short Bs[3][BNS * BKG];   // 3 x 8 KB = 48 KB
    const int tid  = threadIdx.x;
    const int wave = tid >> 6;
    const int lane = tid & 63;
    const int wr = wave >> 1, wc = wave & 1;
    const int row0 = blockIdx.y * BMS;
    const int col0 = blockIdx.x * BNS;

    const int g0 = tid, g1 = tid + 256;
    const int ar0 = g0 >> 2, as0 = (g0 & 3) ^ ((ar0 >> 1) & 3);
    const int ar1 = g1 >> 2, as1 = (g1 & 3) ^ ((ar1 >> 1) & 3);
    const unsigned short* Ap0 = A + (size_t)(row0 + ar0) * EMB + as0 * 8;
    const unsigned short* Ap1 = A + (size_t)(row0 + ar1) * EMB + as1 * 8;
    const unsigned short* Bp0 = B + (size_t)(col0 + ar0) * EMB + as0 * 8;
    const unsigned short* Bp1 = B + (size_t)(col0 + ar1) * EMB + as1 * 8;

    const int frow = lane & 15;
    const int kblk = lane >> 4;
    int aoff[4], boff[4];
#pragma unroll
    for (int m = 0; m < 4; ++m) {
        const int r = wr * 64 + m * 16 + frow;
        aoff[m] = (r * 4 + (kblk ^ ((r >> 1) & 3))) * 8;
        const int c = wc * 64 + m * 16 + frow;
        boff[m] = (c * 4 + (kblk ^ ((c >> 1) & 3))) * 8;
    }

    floatx4 acc[4][4];
#pragma unroll
    for (int m = 0; m < 4; ++m)
#pragma unroll
        for (int n = 0; n < 4; ++n)
            acc[m][n] = (floatx4){0.f, 0.f, 0.f, 0.f};

    auto STAGE = [&](int buf, int k0) {
        gload16(Ap0 + k0, &As[buf][g0 * 8]);
        gload16(Ap1 + k0, &As[buf][g1 * 8]);
        gload16(Bp0 + k0, &Bs[buf][g0 * 8]);
        gload16(Bp1 + k0, &Bs[buf][g1 * 8]);
    };

#define LDFRAG_S(buf, af, bf)                                                  \
    {                                                                          \
        _Pragma("unroll")                                                      \
        for (int m = 0; m < 4; ++m) af[m] = *(const short8*)&As[buf][aoff[m]]; \
        _Pragma("unroll")                                                      \
        for (int n = 0; n < 4; ++n) bf[n] = *(const short8*)&Bs[buf][boff[n]]; \
    }
#define MFMA_S(af, bf)                                                         \
    {                                                                          \
        _Pragma("unroll")                                                      \
        for (int m = 0; m < 4; ++m)                                            \
            _Pragma("unroll")                                                  \
            for (int n = 0; n < 4; ++n)                                        \
                acc[m][n] = __builtin_amdgcn_mfma_f32_16x16x32_bf16(           \
                    af[m], bf[n], acc[m][n], 0, 0, 0);                         \
    }

    short8 afA[4], bfA[4], afB[4], bfB[4];
    const int NT = EMB / BKG;   // 24 (even, >= 6)

    // ---- prologue: establish invariant {STAGE(j+2), STAGE(j+3)} in flight ----
    STAGE(0, 0); STAGE(1, BKG); STAGE(2, 2 * BKG);           // 12 outstanding
    asm volatile("s_waitcnt vmcnt(8)" ::: "memory");          // tile0 done
    __builtin_amdgcn_s_barrier();
    asm volatile("" ::: "memory");
    LDFRAG_S(0, afA, bfA);                                    // frags tile0
    asm volatile("s_waitcnt lgkmcnt(0)" ::: "memory");        // frags in regs
    __builtin_amdgcn_s_barrier();                             // buf0 free (all waves)
    asm volatile("" ::: "memory");
    STAGE(0, 3 * BKG);                                        // tile3 -> buf0
    asm volatile("s_waitcnt vmcnt(8)" ::: "memory");          // tile1 done
    __builtin_amdgcn_s_barrier();
    asm volatile("" ::: "memory");
    LDFRAG_S(1, afB, bfB);                                    // frags tile1

    for (int it = 0; it < NT; it += 2) {
        // even tile j=it: MFMA setA; prefetch frags(j+2) into setA
        if (it + 3 < NT) asm volatile("s_waitcnt vmcnt(4) lgkmcnt(0)" ::: "memory");
        else             asm volatile("s_waitcnt vmcnt(0) lgkmcnt(0)" ::: "memory");
        __builtin_amdgcn_s_barrier();
        asm volatile("" ::: "memory");
        if (it + 4 < NT) STAGE((it + 4) % 3, (it + 4) * BKG);
        MFMA_S(afA, bfA);
        if (it + 2 < NT) LDFRAG_S((it + 2) % 3, afA, bfA);

        // odd tile j=it+1: MFMA setB; prefetch frags(j+2) into setB
        if (it + 4 < NT) asm volatile("s_waitcnt vmcnt(4) lgkmcnt(0)" ::: "memory");
        else             asm volatile("s_waitcnt vmcnt(0) lgkmcnt(0)" ::: "memory");
        __builtin_amdgcn_s_barrier();
        asm volatile("" ::: "memory");
        if (it + 5 < NT) STAGE((it + 5) % 3, (it + 5) * BKG);
        MFMA_S(afB, bfB);
        if (it + 3 < NT) LDFRAG_S((it + 3) % 3, afB, bfB);
    }
#undef LDFRAG_S
#undef MFMA_S

    const int crow = row0 + wr * 64 + (lane >> 4) * 4;
    const int ccol = col0 + wc * 64 + (lane & 15);
#pragma unroll
    for (int m = 0; m < 4; ++m)
#pragma unroll
        for (int n = 0; n < 4; ++n)
#pragma unroll
            for (int r = 0; r < 4; ++r)
                C[(size_t)(crow + m * 16 + r) * NCOLS + ccol + n * 16] = f2bf(acc[m][n][r]);
}

// ============ fused prep: out-zero + cvt + IVF gather (dense) + pad-zero + cbprep ===
__global__ __launch_bounds__(256) void prep_kernel(
    const float* __restrict__ q, const float* __restrict__ d,
    const float* __restrict__ n, const float* __restrict__ rot,
    const float* __restrict__ cb, const float* __restrict__ ivf,
    const int* __restrict__ doc_ids, const int* __restrict__ neg_ids,
    unsigned short* __restrict__ qdnb, unsigned short* __restrict__ rotb,
    unsigned short* __restrict__ ccb, unsigned short* __restrict__ subp,
    unsigned short* __restrict__ cbb, float* __restrict__ bias,
    float* __restrict__ out, int out_n)
{
    int i = blockIdx.x * 256 + threadIdx.x;

    if (i < CVT4) {
        const int S1 = NQ * EMB / 4;
        const int S2 = S1 + NQ * EMB / 4;
        const int S3 = S2 + 4096 * EMB / 4;
        const float* src; unsigned short* dst; int off;
        if (i < S1)      { src = q;   dst = qdnb;                        off = i; }
        else if (i < S2) { src = d;   dst = qdnb + (size_t)NQ * EMB;     off = i - S1; }
        else if (i < S3) { src = n;   dst = qdnb + (size_t)2 * NQ * EMB; off = i - S2; }
        else             { src = rot; dst = rotb;                        off = i - S3; }
        const float4 v = ((const float4*)src)[off];
        ushort4 b;
        b.x = f2bf(v.x); b.y = f2bf(v.y); b.z = f2bf(v.z); b.w = f2bf(v.w);
        ((ushort4*)dst)[off] = b;
        return;
    }
    i -= CVT4;

    if (i < GATW) {
        const int row = i / 192, t = i - row * 192;   // dense: all lanes active
        const int id = (row < NQ) ? doc_ids[row] : neg_ids[row - NQ];
        const float4 v = ((const float4*)(ivf + (size_t)id * EMB))[t];
        ushort4 b;
        b.x = f2bf(v.x); b.y = f2bf(v.y); b.z = f2bf(v.z); b.w = f2bf(v.w);
        ((ushort4*)(ccb + (size_t)row * EMB))[t] = b;
        return;
    }
    i -= GATW;

    if (i < PADW) {
        const int nn = i >> 5, mm = i & 31;
        *(uint4*)(subp + (size_t)nn * (MSUB * DPAD) + mm * DPAD + DSUB) =
            make_uint4(0u, 0u, 0u, 0u);
        return;
    }
    i -= PADW;

    if (i < CBPW) {
        const float* cp = cb + (size_t)i * DSUB;
        unsigned short o[DPAD];
        float ss = 0.f;
#pragma unroll
        for (int j = 0; j < 6; ++j) {
            const float4 v = *(const float4*)(cp + j * 4);
            o[j * 4 + 0] = f2bf(v.x); o[j * 4 + 1] = f2bf(v.y);
            o[j * 4 + 2] = f2bf(v.z); o[j * 4 + 3] = f2bf(v.w);
            ss = fmaf(v.x, v.x, ss); ss = fmaf(v.y, v.y, ss);
            ss = fmaf(v.z, v.z, ss); ss = fmaf(v.w, v.w, ss);
        }
#pragma unroll
        for (int j = DSUB; j < DPAD; ++j) o[j] = 0;
        unsigned short* op = cbb + (size_t)i * DPAD;
#pragma unroll
        for (int j = 0; j < DPAD / 4; ++j)
            ((ushort4*)op)[j] = make_ushort4(o[j*4], o[j*4+1], o[j*4+2], o[j*4+3]);
        bias[i] = 0.5f * ss;
        return;
    }
    i -= CBPW;

    if (i < 64 && i < out_n) out[i] = 0.f;
}

// ============ PQ argmin via MFMA + fused reconstruct ============
__global__ __launch_bounds__(256) void pq_mfma_argmin(
    const unsigned short* __restrict__ subp,   // [NTOT][MSUB*DPAD]
    const unsigned short* __restrict__ cbb,    // [MSUB][KCODE][DPAD]
    const float* __restrict__ bias,            // [MSUB][KCODE]
    const unsigned short* __restrict__ ccb,    // [NTOT][EMB]
    unsigned short* __restrict__ pqb)          // [NTOT][EMB]
{
    const int m = blockIdx.y;
    const int row0 = blockIdx.x * 128;
    __shared__ __align__(16) unsigned short As[128 * DPAD];   // 8 KB
    __shared__ __align__(16) unsigned short Bs[KCODE * DPAD]; // 16 KB
    __shared__ __align__(16) float bs[KCODE];                 // 1 KB
    __shared__ unsigned char kbest[128];
    const int tid = threadIdx.x;
    const int wave = tid >> 6, lane = tid & 63;

    {
        const int g = tid;
        const int r = g >> 2, kc = (g & 3) ^ ((r >> 1) & 3);
        gload16(subp + (size_t)(row0 + r) * (MSUB * DPAD) + m * DPAD + kc * 8, &As[g * 8]);
    }
    {
        const int g = tid + 256;
        const int r = g >> 2, kc = (g & 3) ^ ((r >> 1) & 3);
        gload16(subp + (size_t)(row0 + r) * (MSUB * DPAD) + m * DPAD + kc * 8, &As[g * 8]);
    }
#pragma unroll
    for (int i = 0; i < 4; ++i) {
        const int g = tid + i * 256;
        const int r = g >> 2, kc = (g & 3) ^ ((r >> 1) & 3);
        gload16(cbb + (size_t)m * (KCODE * DPAD) + r * DPAD + kc * 8, &Bs[g * 8]);
    }
    if (tid < 64) gload16(bias + m * KCODE + tid * 4, &bs[tid * 4]);
    __syncthreads();

    const int frow = lane & 15, kblk = lane >> 4;
    short8 af[2];
#pragma unroll
    for (int t = 0; t < 2; ++t) {
        const int r = wave * 32 + t * 16 + frow;
        af[t] = *(const short8*)&As[(r * 4 + (kblk ^ ((r >> 1) & 3))) * 8];
    }
    unsigned best[2][4];
#pragma unroll
    for (int t = 0; t < 2; ++t)
#pragma unroll
        for (int r = 0; r < 4; ++r) best[t][r] = 0xFFFFFFFFu;

#pragma unroll
    for (int n = 0; n < 16; ++n) {
        const int br = n * 16 + frow;
        const short8 bf = *(const short8*)&Bs[(br * 4 + (kblk ^ ((br >> 1) & 3))) * 8];
        const float bv = bs[br];
        const unsigned kid = (unsigned)br;
        floatx4 a0 = __builtin_amdgcn_mfma_f32_16x16x32_bf16(
            af[0], bf, (floatx4){0.f, 0.f, 0.f, 0.f}, 0, 0, 0);
        floatx4 a1 = __builtin_amdgcn_mfma_f32_16x16x32_bf16(
            af[1], bf, (floatx4){0.f, 0.f, 0.f, 0.f}, 0, 0, 0);
#pragma unroll
        for (int r = 0; r < 4; ++r) {
            const float d0 = bv - a0[r];
            const float d1 = bv - a1[r];
            unsigned u0 = __float_as_uint(d0); u0 ^= (unsigned)((int)u0 >> 31) | 0x80000000u;
            unsigned u1 = __float_as_uint(d1); u1 ^= (unsigned)((int)u1 >> 31) | 0x80000000u;
            best[0][r] = min(best[0][r], (u0 & 0xFFFFFF00u) | kid);
            best[1][r] = min(best[1][r], (u1 & 0xFFFFFF00u) | kid);
        }
    }
#pragma unroll
    for (int off = 1; off <= 8; off <<= 1)
#pragma unroll
        for (int t = 0; t < 2; ++t)
#pragma unroll
            for (int r = 0; r < 4; ++r)
                best[t][r] = min(best[t][r], (unsigned)__shfl_xor((int)best[t][r], off));
    if (frow == 0) {
        const int rbase = wave * 32 + kblk * 4;
#pragma unroll
        for (int t = 0; t < 2; ++t)
#pragma unroll
            for (int r = 0; r < 4; ++r)
                kbest[rbase + t * 16 + r] = (unsigned char)(best[t][r] & 0xFFu);
    }
    __syncthreads();

    if (tid < 128) {
        const int row = row0 + tid;
        const int k = kbest[tid];
        const unsigned short* cbp = cbb + ((size_t)m * KCODE + k) * DPAD;
        const unsigned short* ccp = ccb + (size_t)row * EMB + m * DSUB;
        unsigned short* op = pqb + (size_t)row * EMB + m * DSUB;
#pragma unroll
        for (int j = 0; j < 6; ++j) {
            const ushort4 cw = ((const ushort4*)cbp)[j];
            const ushort4 cc = ((const ushort4*)ccp)[j];
            ushort4 o;
            o.x = f2bf(bf2f(cw.x) + bf2f(cc.x)); o.y = f2bf(bf2f(cw.y) + bf2f(cc.y));
            o.z = f2bf(bf2f(cw.z) + bf2f(cc.z)); o.w = f2bf(bf2f(cw.w) + bf2f(cc.w));
            ((ushort4*)op)[j] = o;
        }
    }
}

// ============ loss: block per (row, ls); teacher stats inline; 5 slot reductions ====
__global__ __launch_bounds__(256) void loss3_kernel(
    const unsigned short* __restrict__ Tb, const unsigned short* __restrict__ S0b,
    const unsigned short* __restrict__ S1b, const unsigned short* __restrict__ S2b,
    float* __restrict__ out, float scale)
{
    const int row = blockIdx.x;
    const int ls = blockIdx.y;
    const unsigned short* S = (ls == 0) ? S0b : ((ls == 1) ? S1b : S2b);
    const int t = threadIdx.x, wid = t >> 6, lane = t & 63;
    __shared__ float red[5][4];

    auto blk_max = [&](float v, int slot) -> float {
#pragma unroll
        for (int off = 32; off >= 1; off >>= 1) v = fmaxf(v, __shfl_xor(v, off));
        if (lane == 0) red[slot][wid] = v;
        __syncthreads();
        return fmaxf(fmaxf(red[slot][0], red[slot][1]),
                     fmaxf(red[slot][2], red[slot][3]));
    };
    auto blk_sum = [&](float v, int slot) -> float {
#pragma unroll
        for (int off = 32; off >= 1; off >>= 1) v += __shfl_xor(v, off);
        if (lane == 0) red[slot][wid] = v;
        __syncthreads();
        return red[slot][0] + red[slot][1] + red[slot][2] + red[slot][3];
    };

    const ushort4* t4 = (const ushort4*)(Tb + (size_t)row * NCOLS);
    const ushort4* s4 = (const ushort4*)(S + (size_t)row * NCOLS);
    float tv[20], sv[20];
#pragma unroll
    for (int i = 0; i < 5; ++i) {
        const ushort4 ut = t4[t + i * 256];
        const ushort4 us = s4[t + i * 256];
        tv[i*4+0] = bf2f(ut.x); tv[i*4+1] = bf2f(ut.y);
        tv[i*4+2] = bf2f(ut.z); tv[i*4+3] = bf2f(ut.w);
        sv[i*4+0] = bf2f(us.x); sv[i*4+1] = bf2f(us.y);
        sv[i*4+2] = bf2f(us.z); sv[i*4+3] = bf2f(us.w);
    }

    float pm = -3.4e38f, qm = -3.4e38f;
#pragma unroll
    for (int j = 0; j < 20; ++j) { pm = fmaxf(pm, tv[j]); qm = fmaxf(qm, sv[j]); }
    const float tm = blk_max(pm, 0);
    const float sm = blk_max(qm, 1);

    float ps = 0.f, ss = 0.f;
#pragma unroll
    for (int j = 0; j < 20; ++j) {
        ps += __builtin_amdgcn_exp2f((tv[j] - tm) * L2E);
        ss += __builtin_amdgcn_exp2f((sv[j] - sm) * L2E);
    }
    const float inv_t = 1.f / blk_sum(ps, 2);
    const float inv_s = 1.f / blk_sum(ss, 3);

    float acc = 0.f;
#pragma unroll
    for (int j = 0; j < 20; ++j) {
        const float tp = __builtin_amdgcn_exp2f((tv[j] - tm) * L2E) * inv_t;
        acc += tp * __builtin_amdgcn_logf(
            __builtin_amdgcn_exp2f((sv[j] - sm) * L2E) * inv_s + 1e-6f);
    }
    const float tot = blk_sum(acc, 4);
    if (t == 0) atomicAdd(out + ls, -tot * LN2 * scale);
}

// ============ launch ============
extern "C" void kernel_launch(void* const* d_in, const int* in_sizes, int n_in,
                              void* d_out, int out_size, void* d_ws, size_t ws_size,
                              hipStream_t stream)
{
    const float* q    = (const float*)d_in[0];
    const float* dpos = (const float*)d_in[1];
    const float* nneg = (const float*)d_in[2];
    const float* rot  = (const float*)d_in[3];
    const float* cb   = (const float*)d_in[4];
    const float* ivf  = (const float*)d_in[5];
    const int* doc_ids = (const int*)d_in[6];
    const int* neg_ids = (const int*)d_in[7];
    float* out = (float*)d_out;

    char* p = (char*)d_ws;
    auto take = [&](size_t bytes) { char* r = p; p += (bytes + 255) & ~(size_t)255; return r; };
    unsigned short* qdnb  = (unsigned short*)take((size_t)(NQ + NTOT) * EMB * 2);
    unsigned short* rqdnb = (unsigned short*)take((size_t)(NQ + NTOT) * EMB * 2);
    unsigned short* rotb  = (unsigned short*)take((size_t)EMB * EMB * 2);
    unsigned short* ccb   = (unsigned short*)take((size_t)NTOT * EMB * 2);
    unsigned short* pqb   = (unsigned short*)take((size_t)NTOT * EMB * 2);
    unsigned short* cbb   = (unsigned short*)take((size_t)MSUB * KCODE * DPAD * 2);
    float*          bias  = (float*)take((size_t)MSUB * KCODE * 4);
    unsigned short* subp  = (unsigned short*)take((size_t)NTOT * MSUB * DPAD * 2);
    unsigned short* Tb    = (unsigned short*)take((size_t)NQ * NCOLS * 2);
    unsigned short* S0b   = (unsigned short*)take((size_t)NQ * NCOLS * 2);
    unsigned short* S1b   = (unsigned short*)take((size_t)NQ * NCOLS * 2);
    unsigned short* S2b   = (unsigned short*)take((size_t)NQ * NCOLS * 2);

    unsigned short* qb   = qdnb;
    unsigned short* dnb  = qdnb + (size_t)NQ * EMB;
    unsigned short* rqb  = rqdnb;
    unsigned short* rdnb = rqdnb + (size_t)NQ * EMB;

    const float scale = 1.f / NQ;

    // 1) fused prep: out-zero + cvt + IVF gather (dense) + subp-pad-zero + cbprep
    const int prepW = CVT4 + GATW + PADW + CBPW + 64;
    prep_kernel<<<(prepW + 255) / 256, 256, 0, stream>>>(
        q, dpos, nneg, rot, cb, ivf, doc_ids, neg_ids,
        qdnb, rotb, ccb, subp, cbb, bias, out, out_size);

    // 2) rotation: [q;d;n] @ rot^T -> rqdnb bf16; rows >= NQ also subp residual
    gemm_rot<<<dim3(EMB / BNR, (NQ + NTOT) / BMR), 256, 0, stream>>>(
        qdnb, rotb, rqdnb, ccb, subp);

    // 3) PQ argmin (MFMA) with fused reconstruct -> pqb
    pq_mfma_argmin<<<dim3(NTOT / 128, MSUB), 256, 0, stream>>>(
        subp, cbb, bias, ccb, pqb);

    // 4) all four score GEMMs in one z=4 dispatch (bf16 outputs)
    gemm_score4<<<dim3(NCOLS / BNS, NQ / BMS, 4), 256, 0, stream>>>(
        qb, dnb, Tb,  rqb, rdnb, S0b,  rqb, ccb, S1b,  rqb, pqb, S2b);

    // 5) three losses, block per (row, ls)
    loss3_kernel<<<dim3(NQ, 3), 256, 0, stream>>>(Tb, S0b, S1b, S2b, out, scale);
}